// Round 21
// baseline (120.972 us; speedup 1.0000x reference)
//
#include <hip/hip_runtime.h>
#include <hip/hip_bf16.h>

#define NB 4
#define LSEQ 2048
#define NH 16
#define HD 64
#define EMB 1024

typedef __attribute__((ext_vector_type(8))) short bf16x8;
typedef __attribute__((ext_vector_type(4))) float f32x4;
typedef __attribute__((ext_vector_type(16))) float f32x16;
typedef __attribute__((ext_vector_type(2))) unsigned int uint2v;

__device__ __forceinline__ unsigned short f2bf(float x) {
    union { float f; unsigned u; } v; v.f = x;
    unsigned r = v.u + 0x7fff + ((v.u >> 16) & 1);   // round-to-nearest-even
    return (unsigned short)(r >> 16);
}

__device__ __forceinline__ float exp2_fast(float x) {
#if __has_builtin(__builtin_amdgcn_exp2f)
    return __builtin_amdgcn_exp2f(x);
#else
    float r; asm("v_exp_f32 %0, %1\n\ts_nop 1" : "=v"(r) : "v"(x)); return r;
#endif
}

// pack two f32 -> one u32 of 2 bf16, round-to-nearest (epilogue only)
__device__ __forceinline__ unsigned pack_bf2(float lo, float hi) {
    union { __hip_bfloat162 h2; unsigned u; } cv;
    cv.h2 = __float22bfloat162_rn(make_float2(lo, hi));
    return cv.u;
}

// pack two f32 -> one u32 of 2 bf16 by TRUNCATION: single v_perm_b32.
__device__ __forceinline__ unsigned pack_bf2_trunc(float lo, float hi) {
    union { float f; unsigned u; } a, b;
    a.f = lo; b.f = hi;
    return __builtin_amdgcn_perm(b.u, a.u, 0x07060302u);
}

// v_permlane32_swap_b32: a.row1 <-> b.row0
__device__ __forceinline__ void plswap(unsigned &a, unsigned &b) {
#if __has_builtin(__builtin_amdgcn_permlane32_swap)
    uint2v r = __builtin_amdgcn_permlane32_swap(a, b, false, false);
    a = r[0]; b = r[1];
#else
    asm volatile("s_nop 0\n\tv_permlane32_swap_b32 %0, %1\n\ts_nop 0"
                 : "+v"(a), "+v"(b));
#endif
}

__device__ __forceinline__ void async16(void* lds, const void* g) {
    __builtin_amdgcn_global_load_lds(
        (const __attribute__((address_space(1))) unsigned int*)g,
        (__attribute__((address_space(3))) unsigned int*)lds, 16, 0, 0);
}

// ---------------------------------------------------------------- wconv ----
__global__ void wconv_kernel(const float* __restrict__ Wf, unsigned short* __restrict__ Wb) {
    int i = (blockIdx.x * 256 + threadIdx.x) * 4;
    float4 v = *(const float4*)(Wf + i);
    ushort4 o = { f2bf(v.x), f2bf(v.y), f2bf(v.z), f2bf(v.w) };
    *(ushort4*)(Wb + i) = o;
}

// -------------------------------------------------------------- prep_all ----
// One launch, three concurrent parts. Fragment-direct layouts:
//   K: per (nh, tile32 tau): 4KB image; 16B chunk (c=2dk+hl, key&31) at
//      ((c<<5)+(key&31))<<3 shorts.
//   V: per (nh, tile32): 4KB image; chunk (c2=2ks+hl, d) at ((c2<<6)+d)<<3.
__global__ void prep_all(const float* __restrict__ Wf, unsigned short* __restrict__ Wb,
                         const float* __restrict__ Kf, unsigned short* __restrict__ Kb,
                         const float* __restrict__ Vf, unsigned short* __restrict__ Vt)
{
    __shared__ float T[64][65];
    const int tid = threadIdx.x;
    const int b = blockIdx.x;

    if (b < 1024) {
        int i = (b * 256 + tid) * 4;
        float4 v = *(const float4*)(Wf + i);
        ushort4 o = { f2bf(v.x), f2bf(v.y), f2bf(v.z), f2bf(v.w) };
        *(ushort4*)(Wb + i) = o;
        return;
    }
    if (b < 5120) {
        int idx = (b - 1024) * 256 + tid;    // 2^20 total
        int c   = idx & 7;                   // chunk = 2*dk + hl
        int key = (idx >> 3) & 2047;
        int h   = (idx >> 14) & 15;
        int n   = idx >> 18;
        const float* src = Kf + (size_t)(n * LSEQ + key) * EMB + h * HD + c * 8;
        float4 a = *(const float4*)src;
        float4 bb = *(const float4*)(src + 4);
        unsigned short* dst = Kb + ((size_t)((n * NH + h) * 64 + (key >> 5)) << 11)
                                 + (((c << 5) + (key & 31)) << 3);
        ushort4 o0 = { f2bf(a.x), f2bf(a.y), f2bf(a.z), f2bf(a.w) };
        ushort4 o1 = { f2bf(bb.x), f2bf(bb.y), f2bf(bb.z), f2bf(bb.w) };
        *(ushort4*)dst = o0;
        *(ushort4*)(dst + 4) = o1;
        return;
    }
    {
        const int vb = b - 5120;             // (n*16+h)*32 + kt64
        const int kt = vb & 31, h = (vb >> 5) & 15, n = vb >> 9;
        const float* src = Vf + (size_t)(n * LSEQ + kt * 64) * EMB + h * HD;
        (void)n; (void)h; (void)kt;

        for (int i = tid; i < 1024; i += 256) {          // 64 keys x 16 float4
            const int key = i >> 4;
            const int c4  = (i & 15) * 4;
            const float4 v = *(const float4*)(src + (size_t)key * EMB + c4);
            T[key][c4 + 0] = v.x; T[key][c4 + 1] = v.y;
            T[key][c4 + 2] = v.z; T[key][c4 + 3] = v.w;
        }
        __syncthreads();
        // emit two 32-key tiles: tile = vb*2 + half; chunk c2 (8 keys) x row d
        for (int i = tid; i < 512; i += 256) {           // 64 d x 2 half x 4 c2
            const int d = i >> 3, half = (i >> 2) & 1, c2 = i & 3;
            const int k0 = half * 32 + c2 * 8;
            ushort4 o0 = { f2bf(T[k0 + 0][d]), f2bf(T[k0 + 1][d]),
                           f2bf(T[k0 + 2][d]), f2bf(T[k0 + 3][d]) };
            ushort4 o1 = { f2bf(T[k0 + 4][d]), f2bf(T[k0 + 5][d]),
                           f2bf(T[k0 + 6][d]), f2bf(T[k0 + 7][d]) };
            unsigned short* p = Vt + ((size_t)(vb * 2 + half) << 11)
                                   + (((c2 << 6) + d) << 3);
            *(ushort4*)p = o0;
            *(ushort4*)(p + 4) = o1;
        }
    }
}

// ------------------------------------------------------------- attention ----
// attn20: round-19's key-split kernel with the spill bug fixed: launch
// bounds (256,2) (NOT (256,3) which capped VGPR at 84 -> scratch spill).
// 4 waves = {wq 0..1} x {kh 0..1 key-halves}; per-wave body identical to
// attn18 (64 q, reg-dbuf K/V, trunc-pack P, matrix l-sum); partials
// combined via LDS (shift-free softmax -> exact). grid 1024: LDS 33KB and
// ~124 VGPR both allow 4 blocks/CU -> up to 4 waves/SIMD (vs 2 before).

__device__ __forceinline__ void attn20_body(
    const bf16x8 (&KF)[4], const bf16x8 (&VF)[4],
    const bf16x8 (&qf)[2][4], const bf16x8 ones, const int hl, const int l31,
    f32x16 (&oaccT)[2][2], f32x16 (&lacc)[2])
{
    // ---- S^T = K x Q (32 keys x 64 q), log2-domain ----
    f32x16 sk[2];
    #pragma unroll
    for (int g = 0; g < 2; ++g)
        #pragma unroll
        for (int e = 0; e < 16; ++e) sk[g][e] = 0.f;
    #pragma unroll
    for (int dk = 0; dk < 4; ++dk)
        #pragma unroll
        for (int g = 0; g < 2; ++g)
            sk[g] = __builtin_amdgcn_mfma_f32_32x32x16_bf16(KF[dk], qf[g][dk], sk[g], 0, 0, 0);

    // ---- p = 2^s; trunc-pack + cross-half swap -> PV B-frags ----
    unsigned wgt[2][4][2];
    #pragma unroll
    for (int g = 0; g < 2; ++g) {
        float p[16];
        #pragma unroll
        for (int e = 0; e < 16; ++e) p[e] = exp2_fast(sk[g][e]);
        #pragma unroll
        for (int gg = 0; gg < 4; ++gg) {
            wgt[g][gg][0] = pack_bf2_trunc(p[4 * gg + 0], p[4 * gg + 1]);
            wgt[g][gg][1] = pack_bf2_trunc(p[4 * gg + 2], p[4 * gg + 3]);
        }
        plswap(wgt[g][0][0], wgt[g][1][0]); plswap(wgt[g][0][1], wgt[g][1][1]);
        plswap(wgt[g][2][0], wgt[g][3][0]); plswap(wgt[g][2][1], wgt[g][3][1]);
    }

    // ---- O^T += V^T x P ; l += ones x P (matrix pipe, same trunc P) ----
    #pragma unroll
    for (int ks = 0; ks < 2; ++ks) {
        union { unsigned u[4]; bf16x8 v; } pu[2];
        #pragma unroll
        for (int g = 0; g < 2; ++g) {
            pu[g].u[0] = wgt[g][2 * ks + 0][0];
            pu[g].u[1] = wgt[g][2 * ks + 0][1];
            pu[g].u[2] = wgt[g][2 * ks + 1][0];
            pu[g].u[3] = wgt[g][2 * ks + 1][1];
            lacc[g] = __builtin_amdgcn_mfma_f32_32x32x16_bf16(ones, pu[g].v, lacc[g], 0, 0, 0);
        }
        #pragma unroll
        for (int db = 0; db < 2; ++db)
            #pragma unroll
            for (int g = 0; g < 2; ++g)
                oaccT[g][db] = __builtin_amdgcn_mfma_f32_32x32x16_bf16(VF[ks * 2 + db], pu[g].v, oaccT[g][db], 0, 0, 0);
    }
}

__global__ __launch_bounds__(256, 2)
void attn20_kernel(const float* __restrict__ Qq, const unsigned short* __restrict__ Kb,
                   const unsigned short* __restrict__ Vt, unsigned short* __restrict__ X)
{
    __shared__ float Po[2][2][2][64][16];   // wq, g, db, lane, e  (32 KB)
    __shared__ float Pl[2][2][64];          // wq, g, lane (1 KB)

    const int tid  = threadIdx.x;
    const int lane = tid & 63;
    const int w    = tid >> 6;           // 0..3
    const int wq   = w & 1;              // q sub-tile (64 q)
    const int kh   = w >> 1;             // key half
    const int l31  = lane & 31;
    const int hl   = lane >> 5;          // half-wave id
    const int l    = ((blockIdx.x & 7) << 7) + (blockIdx.x >> 3);  // XCD-chunked
    const int nh   = l >> 4;             // 0..63
    const int qtile = l & 15;            // 0..15
    const int n = nh >> 4, h = nh & 15;
    const int qrow0 = qtile * 128 + wq * 64;

    // ones A-fragment for the l-sum MFMA
    bf16x8 ones;
    #pragma unroll
    for (int e = 0; e < 8; ++e) ones[e] = (short)0x3F80;

    // Q fragments (B-operand), 2 q-groups of 32: lane q = g*32 + l31
    const float qscale = 0.03125f * 1.44269504f;   // (1/sqrt(1024)) * log2e
    bf16x8 qf[2][4];
    #pragma unroll
    for (int g = 0; g < 2; ++g) {
        const float* qp = Qq + (size_t)(n * LSEQ + qrow0 + g * 32 + l31) * EMB + h * HD + hl * 8;
        #pragma unroll
        for (int dk = 0; dk < 4; ++dk) {
            bf16x8 t;
            #pragma unroll
            for (int e = 0; e < 8; ++e) t[e] = (short)f2bf(qp[dk * 16 + e] * qscale);
            qf[g][dk] = t;
        }
    }

    f32x16 oaccT[2][2];   // [g][db]: O^T[d][q]
    f32x16 lacc[2];       // [g]: every row = sum_k trunc(P)[k][q]
    #pragma unroll
    for (int g = 0; g < 2; ++g) {
        #pragma unroll
        for (int e = 0; e < 16; ++e) lacc[g][e] = 0.f;
        #pragma unroll
        for (int db = 0; db < 2; ++db)
            #pragma unroll
            for (int e = 0; e < 16; ++e) oaccT[g][db][e] = 0.f;
    }

    const unsigned short* kg0 = Kb + ((size_t)nh << 17);
    const unsigned short* vg0 = Vt + ((size_t)nh << 17);

    bf16x8 kA[4], kB[4], vA[4], vB[4];
    auto LOADKV = [&](bf16x8 (&KF)[4], bf16x8 (&VF)[4], int tau) {
        const unsigned short* kb_ = kg0 + ((size_t)tau << 11);
        const unsigned short* vb_ = vg0 + ((size_t)tau << 11);
        #pragma unroll
        for (int dk = 0; dk < 4; ++dk)
            KF[dk] = *(const bf16x8*)(kb_ + ((((dk << 1) + hl) << 5) + l31) * 8);
        #pragma unroll
        for (int i = 0; i < 4; ++i) {
            const int ks = i >> 1, db = i & 1;
            VF[i] = *(const bf16x8*)(vb_ + ((((ks << 1) + hl) << 6) + (db << 5) + l31) * 8);
        }
    };

    const int tau0 = kh * 32;            // this wave's 32 tiles
    LOADKV(kA, vA, tau0);
    LOADKV(kB, vB, tau0 + 1);
    for (int tt = 0; tt < 16; ++tt) {    // 32 tiles, 2 per iteration
        attn20_body(kA, vA, qf, ones, hl, l31, oaccT, lacc);
        if (tt < 15) LOADKV(kA, vA, tau0 + 2 * tt + 2);
        attn20_body(kB, vB, qf, ones, hl, l31, oaccT, lacc);
        if (tt < 15) LOADKV(kB, vB, tau0 + 2 * tt + 3);
    }

    // ---- combine key halves through LDS ----
    if (kh) {
        #pragma unroll
        for (int g = 0; g < 2; ++g) {
            #pragma unroll
            for (int db = 0; db < 2; ++db) {
                float4* dst = (float4*)&Po[wq][g][db][lane][0];
                const f32x16 o = oaccT[g][db];
                dst[0] = make_float4(o[0],  o[1],  o[2],  o[3]);
                dst[1] = make_float4(o[4],  o[5],  o[6],  o[7]);
                dst[2] = make_float4(o[8],  o[9],  o[10], o[11]);
                dst[3] = make_float4(o[12], o[13], o[14], o[15]);
            }
            Pl[wq][g][lane] = lacc[g][0];
        }
    }
    __syncthreads();
    if (kh) return;

    // ---- lower-half waves: add partials, normalize, transpose, store ----
    #pragma unroll
    for (int g = 0; g < 2; ++g) {
        const float ltot = lacc[g][0] + Pl[wq][g][lane];
        const float rcp = 1.0f / ltot;
        #pragma unroll
        for (int db = 0; db < 2; ++db) {
            const float4* src = (const float4*)&Po[wq][g][db][lane][0];
            const float4 a0 = src[0], a1 = src[1], a2 = src[2], a3 = src[3];
            oaccT[g][db][0]  += a0.x; oaccT[g][db][1]  += a0.y;
            oaccT[g][db][2]  += a0.z; oaccT[g][db][3]  += a0.w;
            oaccT[g][db][4]  += a1.x; oaccT[g][db][5]  += a1.y;
            oaccT[g][db][6]  += a1.z; oaccT[g][db][7]  += a1.w;
            oaccT[g][db][8]  += a2.x; oaccT[g][db][9]  += a2.y;
            oaccT[g][db][10] += a2.z; oaccT[g][db][11] += a2.w;
            oaccT[g][db][12] += a3.x; oaccT[g][db][13] += a3.y;
            oaccT[g][db][14] += a3.z; oaccT[g][db][15] += a3.w;
        }
        unsigned ow0[4][2], ow1[4][2];
        #pragma unroll
        for (int gg = 0; gg < 4; ++gg) {
            ow0[gg][0] = pack_bf2(oaccT[g][0][4 * gg + 0] * rcp, oaccT[g][0][4 * gg + 1] * rcp);
            ow0[gg][1] = pack_bf2(oaccT[g][0][4 * gg + 2] * rcp, oaccT[g][0][4 * gg + 3] * rcp);
            ow1[gg][0] = pack_bf2(oaccT[g][1][4 * gg + 0] * rcp, oaccT[g][1][4 * gg + 1] * rcp);
            ow1[gg][1] = pack_bf2(oaccT[g][1][4 * gg + 2] * rcp, oaccT[g][1][4 * gg + 3] * rcp);
        }
        #pragma unroll
        for (int gg = 0; gg < 4; ++gg) {
            plswap(ow0[gg][0], ow1[gg][0]);
            plswap(ow0[gg][1], ow1[gg][1]);
        }
        unsigned short* xrow = X + (size_t)(n * LSEQ + qrow0 + g * 32 + l31) * EMB + h * HD + hl * 32;
        #pragma unroll
        for (int gg = 0; gg < 4; ++gg) {
            uint4 st = { ow0[gg][0], ow0[gg][1], ow1[gg][0], ow1[gg][1] };
            *(uint4*)(xrow + 8 * gg) = st;
        }
    }
}

// ---------------------------------------------- round-1 attention (fallback, small ws) ----
#define KPAD 72
#define PPAD 72

__global__ __launch_bounds__(256, 2)
void attn_kernel(const float* __restrict__ Vv, const float* __restrict__ Kk,
                 const float* __restrict__ Qq, unsigned short* __restrict__ X)
{
    __shared__ unsigned short Klds[64 * KPAD];
    __shared__ unsigned short Vtlds[64 * KPAD];
    __shared__ unsigned short Plds[4 * 16 * PPAD];

    const int tid  = threadIdx.x;
    const int lane = tid & 63;
    const int w    = tid >> 6;
    const int l15  = lane & 15;
    const int l4   = lane >> 4;
    const int qtile = blockIdx.x;
    const int nh    = blockIdx.y;
    const int n = nh >> 4, h = nh & 15;

    bf16x8 qf[2];
    {
        const int qrow = qtile * 64 + w * 16 + l15;
        const float* qp = Qq + (size_t)(n * LSEQ + qrow) * EMB + h * HD + l4 * 8;
        for (int kk = 0; kk < 2; ++kk) {
            bf16x8 t;
            #pragma unroll
            for (int e = 0; e < 8; ++e) t[e] = (short)f2bf(qp[kk * 32 + e] * 0.03125f);
            qf[kk] = t;
        }
    }

    f32x4 oacc[4];
    #pragma unroll
    for (int f = 0; f < 4; ++f) oacc[f] = (f32x4){0.f, 0.f, 0.f, 0.f};
    float mrun[4], lrun[4];
    #pragma unroll
    for (int r = 0; r < 4; ++r) { mrun[r] = -1e30f; lrun[r] = 0.f; }

    for (int kt = 0; kt < LSEQ / 64; ++kt) {
        __syncthreads();
        for (int i = tid; i < 1024; i += 256) {
            const int row = i >> 4;
            const int c4  = (i & 15) * 4;
            const size_t gb = (size_t)(n * LSEQ + kt * 64 + row) * EMB + h * HD + c4;
            const float4 kv = *(const float4*)(Kk + gb);
            const float4 vv = *(const float4*)(Vv + gb);
            ushort4 k4 = { f2bf(kv.x), f2bf(kv.y), f2bf(kv.z), f2bf(kv.w) };
            *(ushort4*)&Klds[row * KPAD + c4] = k4;
            Vtlds[(c4 + 0) * KPAD + row] = f2bf(vv.x);
            Vtlds[(c4 + 1) * KPAD + row] = f2bf(vv.y);
            Vtlds[(c4 + 2) * KPAD + row] = f2bf(vv.z);
            Vtlds[(c4 + 3) * KPAD + row] = f2bf(vv.w);
        }
        __syncthreads();

        f32x4 s[4];
        #pragma unroll
        for (int f = 0; f < 4; ++f) {
            f32x4 acc = (f32x4){0.f, 0.f, 0.f, 0.f};
            #pragma unroll
            for (int kk = 0; kk < 2; ++kk) {
                bf16x8 kb = *(const bf16x8*)&Klds[(f * 16 + l15) * KPAD + kk * 32 + l4 * 8];
                acc = __builtin_amdgcn_mfma_f32_16x16x32_bf16(qf[kk], kb, acc, 0, 0, 0);
            }
            s[f] = acc;
        }

        float mnew[4], corr[4];
        #pragma unroll
        for (int r = 0; r < 4; ++r) {
            float m0 = fmaxf(fmaxf(s[0][r], s[1][r]), fmaxf(s[2][r], s[3][r]));
            #pragma unroll
            for (int msk = 1; msk < 16; msk <<= 1) m0 = fmaxf(m0, __shfl_xor(m0, msk));
            mnew[r] = fmaxf(mrun[r], m0);
            corr[r] = __expf(mrun[r] - mnew[r]);
        }
        float psum[4] = {0.f, 0.f, 0.f, 0.f};
        #pragma unroll
        for (int f = 0; f < 4; ++f) {
            #pragma unroll
            for (int r = 0; r < 4; ++r) {
                float p = __expf(s[f][r] - mnew[r]);
                psum[r] += p;
                Plds[(w * 16 + l4 * 4 + r) * PPAD + f * 16 + l15] = f2bf(p);
            }
        }
        #pragma unroll
        for (int r = 0; r < 4; ++r) {
            float t = psum[r];
            #pragma unroll
            for (int msk = 1; msk < 16; msk <<= 1) t += __shfl_xor(t, msk);
            lrun[r] = lrun[r] * corr[r] + t;
            mrun[r] = mnew[r];
        }
        #pragma unroll
        for (int f = 0; f < 4; ++f) {
            #pragma unroll
            for (int r = 0; r < 4; ++r) oacc[f][r] *= corr[r];
        }
        __syncthreads();

        #pragma unroll
        for (int ks = 0; ks < 2; ++ks) {
            bf16x8 pa = *(const bf16x8*)&Plds[(w * 16 + l15) * PPAD + ks * 32 + l4 * 8];
            #pragma unroll
            for (int f = 0; f < 4; ++f) {
                bf16x8 vb = *(const bf16x8*)&Vtlds[(f * 16 + l15) * KPAD + ks * 32 + l4 * 8];
                oacc[f] = __builtin_amdgcn_mfma_f32_16x16x32_bf16(pa, vb, oacc[f], 0, 0, 0);
            }
        }
    }

    #pragma unroll
    for (int f = 0; f < 4; ++f) {
        #pragma unroll
        for (int r = 0; r < 4; ++r) {
            const int qrow = qtile * 64 + w * 16 + l4 * 4 + r;
            const float o = oacc[f][r] / lrun[r];
            X[(size_t)(n * LSEQ + qrow) * EMB + h * HD + f * 16 + l15] = f2bf(o);
        }
    }
}

// ------------------------------------------------------------ projection ----
// proj4: 128x128 tile, BK=64, global_load_lds + swizzled source (rule #21),
// 2-phase dbuf. XCD-chunked mapping.
__global__ __launch_bounds__(256, 2)
void proj4_kernel(const unsigned short* __restrict__ X, const unsigned short* __restrict__ Wb,
                  const float* __restrict__ bias, float* __restrict__ out)
{
    __shared__ unsigned short Al[2][8192];
    __shared__ unsigned short Bl[2][8192];

    const int tid  = threadIdx.x;
    const int lane = tid & 63;
    const int w    = tid >> 6;
    const int l15  = lane & 15;
    const int l4   = lane >> 4;
    const int bid  = blockIdx.x;               // 512
    const int bm   = (bid & 7) * 8 + ((bid >> 3) & 7);
    const int bn   = bid >> 6;
    const int wr = (w >> 1) * 64;
    const int wc = (w & 1) * 64;

    f32x4 acc[4][4];
    #pragma unroll
    for (int i = 0; i < 4; ++i)
        #pragma unroll
        for (int j = 0; j < 4; ++j) acc[i][j] = (f32x4){0.f, 0.f, 0.f, 0.f};

    int srow[4], soff[4];
    #pragma unroll
    for (int j = 0; j < 4; ++j) {
        const int cid = tid + j * 256;          // 0..1023
        srow[j] = cid >> 3;
        const int c = cid & 7;
        soff[j] = ((c ^ (srow[j] & 7)) << 3);   // swizzled source chunk (shorts)
    }

#define PROJ_STAGE(buf, k0)                                                          \
    {                                                                                \
        _Pragma("unroll")                                                            \
        for (int j = 0; j < 4; ++j) {                                                \
            const int cid = tid + j * 256;                                           \
            async16(&Al[buf][cid << 3],                                              \
                    &X [(size_t)(bm * 128 + srow[j]) * EMB + (k0) + soff[j]]);       \
            async16(&Bl[buf][cid << 3],                                              \
                    &Wb[(size_t)(bn * 128 + srow[j]) * EMB + (k0) + soff[j]]);       \
        }                                                                            \
    }

    PROJ_STAGE(0, 0)
    asm volatile("s_waitcnt vmcnt(0)" ::: "memory");
    __syncthreads();

    int cur = 0;
    for (int k0 = 0; k0 < EMB; k0 += 64) {
        if (k0 + 64 < EMB) PROJ_STAGE(cur ^ 1, k0 + 64)

        #pragma unroll
        for (int kk = 0; kk < 2; ++kk) {
            bf16x8 af[4], bfr[4];
            #pragma unroll
            for (int i = 0; i < 4; ++i) {
                const int row = wr + i * 16 + l15;
                af[i] = *(const bf16x8*)&Al[cur][(row << 6) + (((kk * 4 + l4) ^ (row & 7)) << 3)];
            }
            #pragma unroll
            for (int j = 0; j < 4; ++j) {
                const int row = wc + j * 16 + l15;
                bfr[j] = *(const bf16x8*)&Bl[cur][(row << 6) + (((kk * 4 + l4) ^ (row & 7)) << 3)];
            }
            #pragma unroll
            for (int i = 0; i < 4; ++i)
                #pragma unroll
                for (int j = 0; j < 4; ++j)
                    acc[i][j] = __builtin_amdgcn_mfma_f32_16x16x32_bf16(af[i], bfr[j], acc[i][j], 0, 0, 0);
        }

        asm volatile("s_waitcnt vmcnt(0)" ::: "memory");
        __syncthreads();
        cur ^= 1;
    }

    #pragma unroll
    for (int i = 0; i < 4; ++i) {
        const int row = bm * 128 + wr + i * 16 + l4 * 4;
        #pragma unroll
        for (int j = 0; j < 4; ++j) {
            const int col = bn * 128 + wc + j * 16 + l15;
            const float bj = bias[col];
            #pragma unroll
            for (int r = 0; r < 4; ++r)
                out[(size_t)(row + r) * EMB + col] = acc[i][j][r] + bj;
        }
    }
}

// ---------------------------------------------------------------- launch ----
extern "C" void kernel_launch(void* const* d_in, const int* in_sizes, int n_in,
                              void* d_out, int out_size, void* d_ws, size_t ws_size,
                              hipStream_t stream) {
    const float* Vv   = (const float*)d_in[0];
    const float* Kk   = (const float*)d_in[1];
    const float* Qq   = (const float*)d_in[2];
    const float* Wf   = (const float*)d_in[3];
    const float* bias = (const float*)d_in[4];
    float* out = (float*)d_out;

    unsigned short* X  = (unsigned short*)d_ws;                                    // 16 MB
    unsigned short* Wb = (unsigned short*)((char*)d_ws + (size_t)16 * 1024 * 1024); // 2 MB
    const size_t need = (size_t)50 * 1024 * 1024;

    if (ws_size >= need) {
        unsigned short* Kb = (unsigned short*)((char*)d_ws + (size_t)18 * 1024 * 1024); // 16 MB
        unsigned short* Vt = (unsigned short*)((char*)d_ws + (size_t)34 * 1024 * 1024); // 16 MB
        prep_all<<<dim3(7168), 256, 0, stream>>>(Wf, Wb, Kk, Kb, Vv, Vt);
        attn20_kernel<<<dim3(1024), 256, 0, stream>>>(Qq, Kb, Vt, X);
    } else {
        wconv_kernel<<<dim3(EMB * EMB / 1024), 256, 0, stream>>>(Wf, Wb);
        attn_kernel<<<dim3(LSEQ / 64, NB * NH), 256, 0, stream>>>(Vv, Kk, Qq, X);
    }

    proj4_kernel<<<dim3(512), 256, 0, stream>>>(X, Wb, bias, out);
}

// Round 22
// 117.448 us; speedup vs baseline: 1.0300x; 1.0300x over previous
//
#include <hip/hip_runtime.h>
#include <hip/hip_bf16.h>

#define NB 4
#define LSEQ 2048
#define NH 16
#define HD 64
#define EMB 1024

typedef __attribute__((ext_vector_type(8))) short bf16x8;
typedef __attribute__((ext_vector_type(4))) float f32x4;
typedef __attribute__((ext_vector_type(16))) float f32x16;
typedef __attribute__((ext_vector_type(2))) unsigned int uint2v;

__device__ __forceinline__ unsigned short f2bf(float x) {
    union { float f; unsigned u; } v; v.f = x;
    unsigned r = v.u + 0x7fff + ((v.u >> 16) & 1);   // round-to-nearest-even
    return (unsigned short)(r >> 16);
}

__device__ __forceinline__ float exp2_fast(float x) {
#if __has_builtin(__builtin_amdgcn_exp2f)
    return __builtin_amdgcn_exp2f(x);
#else
    float r; asm("v_exp_f32 %0, %1\n\ts_nop 1" : "=v"(r) : "v"(x)); return r;
#endif
}

// pack two f32 -> one u32 of 2 bf16, round-to-nearest (epilogue only)
__device__ __forceinline__ unsigned pack_bf2(float lo, float hi) {
    union { __hip_bfloat162 h2; unsigned u; } cv;
    cv.h2 = __float22bfloat162_rn(make_float2(lo, hi));
    return cv.u;
}

// pack two f32 -> one u32 of 2 bf16 by TRUNCATION: single v_perm_b32.
__device__ __forceinline__ unsigned pack_bf2_trunc(float lo, float hi) {
    union { float f; unsigned u; } a, b;
    a.f = lo; b.f = hi;
    return __builtin_amdgcn_perm(b.u, a.u, 0x07060302u);
}

// v_permlane32_swap_b32: a.row1 <-> b.row0
__device__ __forceinline__ void plswap(unsigned &a, unsigned &b) {
#if __has_builtin(__builtin_amdgcn_permlane32_swap)
    uint2v r = __builtin_amdgcn_permlane32_swap(a, b, false, false);
    a = r[0]; b = r[1];
#else
    asm volatile("s_nop 0\n\tv_permlane32_swap_b32 %0, %1\n\ts_nop 0"
                 : "+v"(a), "+v"(b));
#endif
}

__device__ __forceinline__ void async16(void* lds, const void* g) {
    __builtin_amdgcn_global_load_lds(
        (const __attribute__((address_space(1))) unsigned int*)g,
        (__attribute__((address_space(3))) unsigned int*)lds, 16, 0, 0);
}

// ---------------------------------------------------------------- wconv ----
__global__ void wconv_kernel(const float* __restrict__ Wf, unsigned short* __restrict__ Wb) {
    int i = (blockIdx.x * 256 + threadIdx.x) * 4;
    float4 v = *(const float4*)(Wf + i);
    ushort4 o = { f2bf(v.x), f2bf(v.y), f2bf(v.z), f2bf(v.w) };
    *(ushort4*)(Wb + i) = o;
}

// -------------------------------------------------------------- prep_all ----
// One launch, three concurrent parts. Fragment-direct layouts:
//   K: per (nh, tile32 tau): 4KB image; 16B chunk (c=2dk+hl, key&31) at
//      ((c<<5)+(key&31))<<3 shorts.
//   V: per (nh, tile32): 4KB image; chunk (c2=2ks+hl, d) at ((c2<<6)+d)<<3.
__global__ void prep_all(const float* __restrict__ Wf, unsigned short* __restrict__ Wb,
                         const float* __restrict__ Kf, unsigned short* __restrict__ Kb,
                         const float* __restrict__ Vf, unsigned short* __restrict__ Vt)
{
    __shared__ float T[64][65];
    const int tid = threadIdx.x;
    const int b = blockIdx.x;

    if (b < 1024) {
        int i = (b * 256 + tid) * 4;
        float4 v = *(const float4*)(Wf + i);
        ushort4 o = { f2bf(v.x), f2bf(v.y), f2bf(v.z), f2bf(v.w) };
        *(ushort4*)(Wb + i) = o;
        return;
    }
    if (b < 5120) {
        int idx = (b - 1024) * 256 + tid;    // 2^20 total
        int c   = idx & 7;                   // chunk = 2*dk + hl
        int key = (idx >> 3) & 2047;
        int h   = (idx >> 14) & 15;
        int n   = idx >> 18;
        const float* src = Kf + (size_t)(n * LSEQ + key) * EMB + h * HD + c * 8;
        float4 a = *(const float4*)src;
        float4 bb = *(const float4*)(src + 4);
        unsigned short* dst = Kb + ((size_t)((n * NH + h) * 64 + (key >> 5)) << 11)
                                 + (((c << 5) + (key & 31)) << 3);
        ushort4 o0 = { f2bf(a.x), f2bf(a.y), f2bf(a.z), f2bf(a.w) };
        ushort4 o1 = { f2bf(bb.x), f2bf(bb.y), f2bf(bb.z), f2bf(bb.w) };
        *(ushort4*)dst = o0;
        *(ushort4*)(dst + 4) = o1;
        return;
    }
    {
        const int vb = b - 5120;             // (n*16+h)*32 + kt64
        const int kt = vb & 31, h = (vb >> 5) & 15, n = vb >> 9;
        const float* src = Vf + (size_t)(n * LSEQ + kt * 64) * EMB + h * HD;
        (void)n; (void)h; (void)kt;

        for (int i = tid; i < 1024; i += 256) {          // 64 keys x 16 float4
            const int key = i >> 4;
            const int c4  = (i & 15) * 4;
            const float4 v = *(const float4*)(src + (size_t)key * EMB + c4);
            T[key][c4 + 0] = v.x; T[key][c4 + 1] = v.y;
            T[key][c4 + 2] = v.z; T[key][c4 + 3] = v.w;
        }
        __syncthreads();
        // emit two 32-key tiles: tile = vb*2 + half; chunk c2 (8 keys) x row d
        for (int i = tid; i < 512; i += 256) {           // 64 d x 2 half x 4 c2
            const int d = i >> 3, half = (i >> 2) & 1, c2 = i & 3;
            const int k0 = half * 32 + c2 * 8;
            ushort4 o0 = { f2bf(T[k0 + 0][d]), f2bf(T[k0 + 1][d]),
                           f2bf(T[k0 + 2][d]), f2bf(T[k0 + 3][d]) };
            ushort4 o1 = { f2bf(T[k0 + 4][d]), f2bf(T[k0 + 5][d]),
                           f2bf(T[k0 + 6][d]), f2bf(T[k0 + 7][d]) };
            unsigned short* p = Vt + ((size_t)(vb * 2 + half) << 11)
                                   + (((c2 << 6) + d) << 3);
            *(ushort4*)p = o0;
            *(ushort4*)(p + 4) = o1;
        }
    }
}

// ------------------------------------------------------------- attention ----
// attn18: LDS-free, barrier-free, 64 q/wave; 2-deep register double-buffer
// for BOTH K and V (slot consumed by body t is immediately re-loaded for
// tile t+2 -> ~2 bodies of latency cover); trunc-pack P via v_perm;
// l-sum on the matrix pipe (same truncated P -> bias cancels in the ratio).
// grid: 512 blocks. l = (bx&7)*64 + bx>>3 (XCD-chunked); nh=l>>3; qtile=l&7.

__device__ __forceinline__ void attn18_body(
    const bf16x8 (&KF)[4], const bf16x8 (&VF)[4],
    const bf16x8 (&qf)[2][4], const bf16x8 ones, const int hl, const int l31,
    f32x16 (&oaccT)[2][2], f32x16 (&lacc)[2])
{
    // ---- S^T = K x Q (32 keys x 64 q), log2-domain ----
    f32x16 sk[2];
    #pragma unroll
    for (int g = 0; g < 2; ++g)
        #pragma unroll
        for (int e = 0; e < 16; ++e) sk[g][e] = 0.f;
    #pragma unroll
    for (int dk = 0; dk < 4; ++dk)
        #pragma unroll
        for (int g = 0; g < 2; ++g)
            sk[g] = __builtin_amdgcn_mfma_f32_32x32x16_bf16(KF[dk], qf[g][dk], sk[g], 0, 0, 0);

    // ---- p = 2^s; trunc-pack (1 v_perm per pair) + cross-half swap ----
    unsigned wgt[2][4][2];
    #pragma unroll
    for (int g = 0; g < 2; ++g) {
        float p[16];
        #pragma unroll
        for (int e = 0; e < 16; ++e) p[e] = exp2_fast(sk[g][e]);
        #pragma unroll
        for (int gg = 0; gg < 4; ++gg) {
            wgt[g][gg][0] = pack_bf2_trunc(p[4 * gg + 0], p[4 * gg + 1]);
            wgt[g][gg][1] = pack_bf2_trunc(p[4 * gg + 2], p[4 * gg + 3]);
        }
        plswap(wgt[g][0][0], wgt[g][1][0]); plswap(wgt[g][0][1], wgt[g][1][1]);
        plswap(wgt[g][2][0], wgt[g][3][0]); plswap(wgt[g][2][1], wgt[g][3][1]);
    }

    // ---- O^T += V^T x P ; l += ones x P (matrix pipe, same trunc P) ----
    #pragma unroll
    for (int ks = 0; ks < 2; ++ks) {
        union { unsigned u[4]; bf16x8 v; } pu[2];
        #pragma unroll
        for (int g = 0; g < 2; ++g) {
            pu[g].u[0] = wgt[g][2 * ks + 0][0];
            pu[g].u[1] = wgt[g][2 * ks + 0][1];
            pu[g].u[2] = wgt[g][2 * ks + 1][0];
            pu[g].u[3] = wgt[g][2 * ks + 1][1];
            lacc[g] = __builtin_amdgcn_mfma_f32_32x32x16_bf16(ones, pu[g].v, lacc[g], 0, 0, 0);
        }
        #pragma unroll
        for (int db = 0; db < 2; ++db)
            #pragma unroll
            for (int g = 0; g < 2; ++g)
                oaccT[g][db] = __builtin_amdgcn_mfma_f32_32x32x16_bf16(VF[ks * 2 + db], pu[g].v, oaccT[g][db], 0, 0, 0);
    }
}

__global__ __launch_bounds__(256, 2)
void attn18_kernel(const float* __restrict__ Qq, const unsigned short* __restrict__ Kb,
                   const unsigned short* __restrict__ Vt, unsigned short* __restrict__ X)
{
    const int tid  = threadIdx.x;
    const int lane = tid & 63;
    const int w    = tid >> 6;
    const int l31  = lane & 31;
    const int hl   = lane >> 5;          // half-wave id
    const int l    = ((blockIdx.x & 7) << 6) + (blockIdx.x >> 3);  // XCD-chunked
    const int nh   = l >> 3;             // 0..63
    const int qtile = l & 7;             // 0..7
    const int n = nh >> 4, h = nh & 15;
    const int qrow0 = qtile * 256 + w * 64;

    // ones A-fragment for the l-sum MFMA
    bf16x8 ones;
    #pragma unroll
    for (int e = 0; e < 8; ++e) ones[e] = (short)0x3F80;

    // Q fragments (B-operand), 2 q-groups of 32: lane q = g*32 + l31
    const float qscale = 0.03125f * 1.44269504f;   // (1/sqrt(1024)) * log2e
    bf16x8 qf[2][4];
    #pragma unroll
    for (int g = 0; g < 2; ++g) {
        const float* qp = Qq + (size_t)(n * LSEQ + qrow0 + g * 32 + l31) * EMB + h * HD + hl * 8;
        #pragma unroll
        for (int dk = 0; dk < 4; ++dk) {
            bf16x8 t;
            #pragma unroll
            for (int e = 0; e < 8; ++e) t[e] = (short)f2bf(qp[dk * 16 + e] * qscale);
            qf[g][dk] = t;
        }
    }

    f32x16 oaccT[2][2];   // [g][db]: O^T[d][q]
    f32x16 lacc[2];       // [g]: every row = sum_k trunc(P)[k][q]
    #pragma unroll
    for (int g = 0; g < 2; ++g) {
        #pragma unroll
        for (int e = 0; e < 16; ++e) lacc[g][e] = 0.f;
        #pragma unroll
        for (int db = 0; db < 2; ++db)
            #pragma unroll
            for (int e = 0; e < 16; ++e) oaccT[g][db][e] = 0.f;
    }

    const unsigned short* kg0 = Kb + ((size_t)nh << 17);
    const unsigned short* vg0 = Vt + ((size_t)nh << 17);

    bf16x8 kA[4], kB[4], vA[4], vB[4];
    auto LOADKV = [&](bf16x8 (&KF)[4], bf16x8 (&VF)[4], int tau) {
        const unsigned short* kb_ = kg0 + ((size_t)tau << 11);
        const unsigned short* vb_ = vg0 + ((size_t)tau << 11);
        #pragma unroll
        for (int dk = 0; dk < 4; ++dk)
            KF[dk] = *(const bf16x8*)(kb_ + ((((dk << 1) + hl) << 5) + l31) * 8);
        #pragma unroll
        for (int i = 0; i < 4; ++i) {
            const int ks = i >> 1, db = i & 1;
            VF[i] = *(const bf16x8*)(vb_ + ((((ks << 1) + hl) << 6) + (db << 5) + l31) * 8);
        }
    };

    LOADKV(kA, vA, 0);
    LOADKV(kB, vB, 1);
    for (int tt = 0; tt < 32; ++tt) {    // 64 tiles, 2 per iteration
        attn18_body(kA, vA, qf, ones, hl, l31, oaccT, lacc);
        if (tt < 31) LOADKV(kA, vA, 2 * tt + 2);      // refill slot A for t+2
        attn18_body(kB, vB, qf, ones, hl, l31, oaccT, lacc);
        if (tt < 31) LOADKV(kB, vB, 2 * tt + 3);      // refill slot B for t+3
    }

    // ---- epilogue per q-group: normalize, permlane-transpose, store ----
    #pragma unroll
    for (int g = 0; g < 2; ++g) {
        const float rcp = 1.0f / lacc[g][0];   // every row of lacc = l[q]
        unsigned ow0[4][2], ow1[4][2];
        #pragma unroll
        for (int gg = 0; gg < 4; ++gg) {
            ow0[gg][0] = pack_bf2(oaccT[g][0][4 * gg + 0] * rcp, oaccT[g][0][4 * gg + 1] * rcp);
            ow0[gg][1] = pack_bf2(oaccT[g][0][4 * gg + 2] * rcp, oaccT[g][0][4 * gg + 3] * rcp);
            ow1[gg][0] = pack_bf2(oaccT[g][1][4 * gg + 0] * rcp, oaccT[g][1][4 * gg + 1] * rcp);
            ow1[gg][1] = pack_bf2(oaccT[g][1][4 * gg + 2] * rcp, oaccT[g][1][4 * gg + 3] * rcp);
        }
        #pragma unroll
        for (int gg = 0; gg < 4; ++gg) {
            plswap(ow0[gg][0], ow1[gg][0]);
            plswap(ow0[gg][1], ow1[gg][1]);
        }
        unsigned short* xrow = X + (size_t)(n * LSEQ + qrow0 + g * 32 + l31) * EMB + h * HD + hl * 32;
        #pragma unroll
        for (int gg = 0; gg < 4; ++gg) {
            uint4 st = { ow0[gg][0], ow0[gg][1], ow1[gg][0], ow1[gg][1] };
            *(uint4*)(xrow + 8 * gg) = st;
        }
    }
}

// ---------------------------------------------- round-1 attention (fallback, small ws) ----
#define KPAD 72
#define PPAD 72

__global__ __launch_bounds__(256, 2)
void attn_kernel(const float* __restrict__ Vv, const float* __restrict__ Kk,
                 const float* __restrict__ Qq, unsigned short* __restrict__ X)
{
    __shared__ unsigned short Klds[64 * KPAD];
    __shared__ unsigned short Vtlds[64 * KPAD];
    __shared__ unsigned short Plds[4 * 16 * PPAD];

    const int tid  = threadIdx.x;
    const int lane = tid & 63;
    const int w    = tid >> 6;
    const int l15  = lane & 15;
    const int l4   = lane >> 4;
    const int qtile = blockIdx.x;
    const int nh    = blockIdx.y;
    const int n = nh >> 4, h = nh & 15;

    bf16x8 qf[2];
    {
        const int qrow = qtile * 64 + w * 16 + l15;
        const float* qp = Qq + (size_t)(n * LSEQ + qrow) * EMB + h * HD + l4 * 8;
        for (int kk = 0; kk < 2; ++kk) {
            bf16x8 t;
            #pragma unroll
            for (int e = 0; e < 8; ++e) t[e] = (short)f2bf(qp[kk * 32 + e] * 0.03125f);
            qf[kk] = t;
        }
    }

    f32x4 oacc[4];
    #pragma unroll
    for (int f = 0; f < 4; ++f) oacc[f] = (f32x4){0.f, 0.f, 0.f, 0.f};
    float mrun[4], lrun[4];
    #pragma unroll
    for (int r = 0; r < 4; ++r) { mrun[r] = -1e30f; lrun[r] = 0.f; }

    for (int kt = 0; kt < LSEQ / 64; ++kt) {
        __syncthreads();
        for (int i = tid; i < 1024; i += 256) {
            const int row = i >> 4;
            const int c4  = (i & 15) * 4;
            const size_t gb = (size_t)(n * LSEQ + kt * 64 + row) * EMB + h * HD + c4;
            const float4 kv = *(const float4*)(Kk + gb);
            const float4 vv = *(const float4*)(Vv + gb);
            ushort4 k4 = { f2bf(kv.x), f2bf(kv.y), f2bf(kv.z), f2bf(kv.w) };
            *(ushort4*)&Klds[row * KPAD + c4] = k4;
            Vtlds[(c4 + 0) * KPAD + row] = f2bf(vv.x);
            Vtlds[(c4 + 1) * KPAD + row] = f2bf(vv.y);
            Vtlds[(c4 + 2) * KPAD + row] = f2bf(vv.z);
            Vtlds[(c4 + 3) * KPAD + row] = f2bf(vv.w);
        }
        __syncthreads();

        f32x4 s[4];
        #pragma unroll
        for (int f = 0; f < 4; ++f) {
            f32x4 acc = (f32x4){0.f, 0.f, 0.f, 0.f};
            #pragma unroll
            for (int kk = 0; kk < 2; ++kk) {
                bf16x8 kb = *(const bf16x8*)&Klds[(f * 16 + l15) * KPAD + kk * 32 + l4 * 8];
                acc = __builtin_amdgcn_mfma_f32_16x16x32_bf16(qf[kk], kb, acc, 0, 0, 0);
            }
            s[f] = acc;
        }

        float mnew[4], corr[4];
        #pragma unroll
        for (int r = 0; r < 4; ++r) {
            float m0 = fmaxf(fmaxf(s[0][r], s[1][r]), fmaxf(s[2][r], s[3][r]));
            #pragma unroll
            for (int msk = 1; msk < 16; msk <<= 1) m0 = fmaxf(m0, __shfl_xor(m0, msk));
            mnew[r] = fmaxf(mrun[r], m0);
            corr[r] = __expf(mrun[r] - mnew[r]);
        }
        float psum[4] = {0.f, 0.f, 0.f, 0.f};
        #pragma unroll
        for (int f = 0; f < 4; ++f) {
            #pragma unroll
            for (int r = 0; r < 4; ++r) {
                float p = __expf(s[f][r] - mnew[r]);
                psum[r] += p;
                Plds[(w * 16 + l4 * 4 + r) * PPAD + f * 16 + l15] = f2bf(p);
            }
        }
        #pragma unroll
        for (int r = 0; r < 4; ++r) {
            float t = psum[r];
            #pragma unroll
            for (int msk = 1; msk < 16; msk <<= 1) t += __shfl_xor(t, msk);
            lrun[r] = lrun[r] * corr[r] + t;
            mrun[r] = mnew[r];
        }
        #pragma unroll
        for (int f = 0; f < 4; ++f) {
            #pragma unroll
            for (int r = 0; r < 4; ++r) oacc[f][r] *= corr[r];
        }
        __syncthreads();

        #pragma unroll
        for (int ks = 0; ks < 2; ++ks) {
            bf16x8 pa = *(const bf16x8*)&Plds[(w * 16 + l15) * PPAD + ks * 32 + l4 * 8];
            #pragma unroll
            for (int f = 0; f < 4; ++f) {
                bf16x8 vb = *(const bf16x8*)&Vtlds[(f * 16 + l15) * KPAD + ks * 32 + l4 * 8];
                oacc[f] = __builtin_amdgcn_mfma_f32_16x16x32_bf16(pa, vb, oacc[f], 0, 0, 0);
            }
        }
    }

    #pragma unroll
    for (int f = 0; f < 4; ++f) {
        #pragma unroll
        for (int r = 0; r < 4; ++r) {
            const int qrow = qtile * 64 + w * 16 + l4 * 4 + r;
            const float o = oacc[f][r] / lrun[r];
            X[(size_t)(n * LSEQ + qrow) * EMB + h * HD + f * 16 + l15] = f2bf(o);
        }
    }
}

// ------------------------------------------------------------ projection ----
// proj4: 128x128 tile, BK=64, global_load_lds + swizzled source (rule #21),
// 2-phase dbuf. XCD-chunked mapping.
__global__ __launch_bounds__(256, 2)
void proj4_kernel(const unsigned short* __restrict__ X, const unsigned short* __restrict__ Wb,
                  const float* __restrict__ bias, float* __restrict__ out)
{
    __shared__ unsigned short Al[2][8192];
    __shared__ unsigned short Bl[2][8192];

    const int tid  = threadIdx.x;
    const int lane = tid & 63;
    const int w    = tid >> 6;
    const int l15  = lane & 15;
    const int l4   = lane >> 4;
    const int bid  = blockIdx.x;               // 512
    const int bm   = (bid & 7) * 8 + ((bid >> 3) & 7);
    const int bn   = bid >> 6;
    const int wr = (w >> 1) * 64;
    const int wc = (w & 1) * 64;

    f32x4 acc[4][4];
    #pragma unroll
    for (int i = 0; i < 4; ++i)
        #pragma unroll
        for (int j = 0; j < 4; ++j) acc[i][j] = (f32x4){0.f, 0.f, 0.f, 0.f};

    int srow[4], soff[4];
    #pragma unroll
    for (int j = 0; j < 4; ++j) {
        const int cid = tid + j * 256;          // 0..1023
        srow[j] = cid >> 3;
        const int c = cid & 7;
        soff[j] = ((c ^ (srow[j] & 7)) << 3);   // swizzled source chunk (shorts)
    }

#define PROJ_STAGE(buf, k0)                                                          \
    {                                                                                \
        _Pragma("unroll")                                                            \
        for (int j = 0; j < 4; ++j) {                                                \
            const int cid = tid + j * 256;                                           \
            async16(&Al[buf][cid << 3],                                              \
                    &X [(size_t)(bm * 128 + srow[j]) * EMB + (k0) + soff[j]]);       \
            async16(&Bl[buf][cid << 3],                                              \
                    &Wb[(size_t)(bn * 128 + srow[j]) * EMB + (k0) + soff[j]]);       \
        }                                                                            \
    }

    PROJ_STAGE(0, 0)
    asm volatile("s_waitcnt vmcnt(0)" ::: "memory");
    __syncthreads();

    int cur = 0;
    for (int k0 = 0; k0 < EMB; k0 += 64) {
        if (k0 + 64 < EMB) PROJ_STAGE(cur ^ 1, k0 + 64)

        #pragma unroll
        for (int kk = 0; kk < 2; ++kk) {
            bf16x8 af[4], bfr[4];
            #pragma unroll
            for (int i = 0; i < 4; ++i) {
                const int row = wr + i * 16 + l15;
                af[i] = *(const bf16x8*)&Al[cur][(row << 6) + (((kk * 4 + l4) ^ (row & 7)) << 3)];
            }
            #pragma unroll
            for (int j = 0; j < 4; ++j) {
                const int row = wc + j * 16 + l15;
                bfr[j] = *(const bf16x8*)&Bl[cur][(row << 6) + (((kk * 4 + l4) ^ (row & 7)) << 3)];
            }
            #pragma unroll
            for (int i = 0; i < 4; ++i)
                #pragma unroll
                for (int j = 0; j < 4; ++j)
                    acc[i][j] = __builtin_amdgcn_mfma_f32_16x16x32_bf16(af[i], bfr[j], acc[i][j], 0, 0, 0);
        }

        asm volatile("s_waitcnt vmcnt(0)" ::: "memory");
        __syncthreads();
        cur ^= 1;
    }

    #pragma unroll
    for (int i = 0; i < 4; ++i) {
        const int row = bm * 128 + wr + i * 16 + l4 * 4;
        #pragma unroll
        for (int j = 0; j < 4; ++j) {
            const int col = bn * 128 + wc + j * 16 + l15;
            const float bj = bias[col];
            #pragma unroll
            for (int r = 0; r < 4; ++r)
                out[(size_t)(row + r) * EMB + col] = acc[i][j][r] + bj;
        }
    }
}

// ---------------------------------------------------------------- launch ----
extern "C" void kernel_launch(void* const* d_in, const int* in_sizes, int n_in,
                              void* d_out, int out_size, void* d_ws, size_t ws_size,
                              hipStream_t stream) {
    const float* Vv   = (const float*)d_in[0];
    const float* Kk   = (const float*)d_in[1];
    const float* Qq   = (const float*)d_in[2];
    const float* Wf   = (const float*)d_in[3];
    const float* bias = (const float*)d_in[4];
    float* out = (float*)d_out;

    unsigned short* X  = (unsigned short*)d_ws;                                    // 16 MB
    unsigned short* Wb = (unsigned short*)((char*)d_ws + (size_t)16 * 1024 * 1024); // 2 MB
    const size_t need = (size_t)50 * 1024 * 1024;

    if (ws_size >= need) {
        unsigned short* Kb = (unsigned short*)((char*)d_ws + (size_t)18 * 1024 * 1024); // 16 MB
        unsigned short* Vt = (unsigned short*)((char*)d_ws + (size_t)34 * 1024 * 1024); // 16 MB
        prep_all<<<dim3(7168), 256, 0, stream>>>(Wf, Wb, Kk, Kb, Vv, Vt);
        attn18_kernel<<<dim3(512), 256, 0, stream>>>(Qq, Kb, Vt, X);
    } else {
        wconv_kernel<<<dim3(EMB * EMB / 1024), 256, 0, stream>>>(Wf, Wb);
        attn_kernel<<<dim3(LSEQ / 64, NB * NH), 256, 0, stream>>>(Vv, Kk, Qq, X);
    }

    proj4_kernel<<<dim3(512), 256, 0, stream>>>(X, Wb, bias, out);
}